// Round 1
// baseline (53843.091 us; speedup 1.0000x reference)
//
#include <hip/hip_runtime.h>

#define T_   256
#define B_   64
#define H_   1024
#define Hh_  512
#define L_   2
#define K1_  1536
#define MAXF 0.875f
#define NBLK 128
#define NT   1024

// ---- ws float offsets ----
#define OFF_WZR1 0u          // [2][64 blk][1536][16]
#define OFF_WG1  3145728u    // [2][64 blk][1536][8]
#define OFF_WZR2 4718592u
#define OFF_WG2  7864320u
#define OFF_XT   9437184u    // [2 buf][1024 k][64 r]
#define OFF_HT   9568256u    // [2 l][2 buf][1024 n][64 r]
#define OFF_ZT   9830400u    // [2 l][512 n][64 r]
#define OFF_RHT  9895936u    // [2 l][512 n][64 r]
#define OFF_CTR  9961472u    // barrier counter (u32)

// Retile: src [L][K1][N] -> dst [L][N/C blocks][K1][C]
__global__ __launch_bounds__(256) void retile_w(const float* __restrict__ src,
                                                float* __restrict__ dst,
                                                int N, int C) {
    size_t tid = (size_t)blockIdx.x * 256 + threadIdx.x;
    size_t total = (size_t)L_ * K1_ * N;
    if (tid >= total) return;
    int c = (int)(tid % C);
    int k = (int)((tid / C) % K1_);
    int b = (int)((tid / ((size_t)C * K1_)) % (N / C));
    int l = (int)(tid / ((size_t)C * K1_ * (N / C)));
    dst[tid] = src[((size_t)l * K1_ + k) * N + b * C + c];
}

// CACHED activation access (L1+L2 path). Cross-XCD visibility is provided by
// the agent release/acquire fences in gbar() (buffer_wbl2 before counter-add,
// buffer_inv after poll), NOT by per-access coherence. Workgroup-scope atomics
// compile to plain global_load/store but are formally ordered by the fences.
__device__ __forceinline__ float ld_act(const float* p) {
    return __hip_atomic_load(p, __ATOMIC_RELAXED, __HIP_MEMORY_SCOPE_WORKGROUP);
}
__device__ __forceinline__ void st_act(float* p, float v) {
    __hip_atomic_store(p, v, __ATOMIC_RELAXED, __HIP_MEMORY_SCOPE_WORKGROUP);
}

// Grid barrier with agent release/acquire semantics:
//  - __syncthreads drains vmcnt -> all this block's stores are in (XCD) L2.
//  - release fence: buffer_wbl2 + wait -> dirty lines flushed to LLC BEFORE
//    the counter increment (flush-before-signal).
//  - after the poll completes (all 128 blocks flushed+signalled), acquire
//    fence: buffer_inv -> L1/L2 dropped, subsequent fills come from LLC
//    which holds the latest values. Monotonic counter, no reset.
__device__ __forceinline__ void gbar(unsigned* ctr, unsigned* target) {
    *target += NBLK;
    __syncthreads();
    if (threadIdx.x == 0) {
        __builtin_amdgcn_fence(__ATOMIC_RELEASE, "agent");
        __hip_atomic_fetch_add(ctr, 1u, __ATOMIC_RELAXED, __HIP_MEMORY_SCOPE_AGENT);
        while (__hip_atomic_load(ctr, __ATOMIC_RELAXED, __HIP_MEMORY_SCOPE_AGENT) < *target)
            __builtin_amdgcn_s_sleep(1);
        __builtin_amdgcn_fence(__ATOMIC_ACQUIRE, "agent");
    }
    __syncthreads();
}

// C[64 r][C cols] = A[64][1536] @ Wt[1536][C].  16-way K-split over waves
// (each A element read once per block, now through L1/L2: the 16 blocks of an
// XCD share one L2 fill of A instead of 16 LLC round-trips each). W from
// L2-hot global, wave-uniform address. Cross-wave reduce via LDS atomicAdd.
template<int C>
__device__ __forceinline__ float phase_gemm(const float* __restrict__ Axlo,
                                            const float* __restrict__ Ahi,
                                            const float* __restrict__ Wt,
                                            float* __restrict__ red) {
    const int tid  = threadIdx.x;
    const int lane = tid & 63;
    const int w    = __builtin_amdgcn_readfirstlane(tid >> 6);  // 0..15
    const int k0   = w * 96;
    for (int i = tid; i < 64 * (C + 1); i += NT) red[i] = 0.f;
    float acc[C];
#pragma unroll
    for (int c = 0; c < C; ++c) acc[c] = 0.f;
    __syncthreads();
#pragma unroll 1
    for (int kb = 0; kb < 96; kb += 8) {
        float av[8];
#pragma unroll
        for (int j = 0; j < 8; ++j) {
            const int k = k0 + kb + j;
            const float* ap = (k < H_) ? (Axlo + (size_t)k * 64)
                                       : (Ahi + (size_t)(k - H_) * 64);
            av[j] = ld_act(ap + lane);
        }
#pragma unroll
        for (int j = 0; j < 8; ++j) {
            const float* wr = Wt + (size_t)(k0 + kb + j) * C;
#pragma unroll
            for (int c = 0; c < C; ++c) acc[c] = fmaf(av[j], wr[c], acc[c]);
        }
    }
#pragma unroll
    for (int c = 0; c < C; ++c) atomicAdd(&red[lane * (C + 1) + c], acc[c]);
    __syncthreads();
    float v = 0.f;
    if (tid < 64 * C) v = red[(tid / C) * (C + 1) + (tid % C)];
    return v;
}

__global__ __launch_bounds__(NT) void revgru_main(
    const int* __restrict__ seq, const float* __restrict__ h0,
    const float* __restrict__ emb,
    const float* __restrict__ bzr1, const float* __restrict__ bg1,
    const float* __restrict__ bzr2, const float* __restrict__ bg2,
    float* __restrict__ ws, float* __restrict__ out)
{
    const int bi = blockIdx.x, tid = threadIdx.x;
    const int l = (bi >= 64) ? 1 : 0, bl = bi & 63;
    __shared__ float red[64 * 17];
    unsigned target = 0;

    float* xT  = ws + OFF_XT;
    float* hT  = ws + OFF_HT;
    float* zT  = ws + OFF_ZT;
    float* rhT = ws + OFF_RHT;
    unsigned* ctr = (unsigned*)(ws + OFF_CTR);

    const float* Wz1  = ws + OFF_WZR1 + ((size_t)l * 64 + bl) * K1_ * 16;
    const float* Wg1l = ws + OFF_WG1  + ((size_t)l * 64 + bl) * K1_ * 8;
    const float* Wz2  = ws + OFF_WZR2 + ((size_t)l * 64 + bl) * K1_ * 16;
    const float* Wg2l = ws + OFF_WG2  + ((size_t)l * 64 + bl) * K1_ * 8;

    const int gtid = bi * NT + tid;            // 0..131071, one elem each
    {   // init: hT[l][buf=1] = h0^T (first step reads buf^1 = 1)
        int ll = gtid >> 16, rem = gtid & 65535, r = rem >> 10, n = rem & 1023;
        st_act(&hT[(((size_t)ll * 2 + 1) * H_ + n) * 64 + r], h0[gtid]);
        if (bi < 64) {  // xT[0] = emb gather for t=0 (65536 elems, blocks 0..63)
            int k = gtid >> 6, rr = gtid & 63;
            st_act(&xT[gtid], emb[(size_t)seq[rr] * H_ + k]);
        }
    }
    gbar(ctr, &target);

    // Pipelined: L0 blocks process t=s, L1 blocks t=s-1.
    for (int s = 0; s <= T_; ++s) {
        const int t = (l == 0) ? s : s - 1;
        const bool act = (t >= 0) && (t < T_);
        const int buf = t & 1;
        float* hC = hT + ((size_t)l * 2 + buf) * (H_ * 64);        // new state
        float* hP = hT + ((size_t)l * 2 + (buf ^ 1)) * (H_ * 64);  // old state
        const float* Ax = (l == 0) ? (xT + (size_t)buf * (H_ * 64))
                                   : (hT + (size_t)buf * (H_ * 64));  // L0 h(t)
        float* zl  = zT  + (size_t)l * Hh_ * 64;
        float* rhl = rhT + (size_t)l * Hh_ * 64;

        // ---- P1: zr1 = [x, h2_old] @ Wzr1 ----
        if (act) {
            float v = phase_gemm<16>(Ax, hP + Hh_ * 64, Wz1, red);
            int r = tid >> 4, c = tid & 15, n = bl * 16 + c;
            v += bzr1[l * H_ + n];
            float sg = 1.f / (1.f + __expf(-v));
            if (n < Hh_) st_act(&zl[n * 64 + r], sg * MAXF + (1.f - MAXF));
            else st_act(&rhl[(n - Hh_) * 64 + r],
                        sg * ld_act(&hP[(size_t)n * 64 + r]));     // r1*h2_old
            if (l == 0 && t + 1 < T_) {   // prefetch x(t+1)
                int k = gtid >> 6, rr = gtid & 63;
                st_act(&xT[(size_t)((t + 1) & 1) * (H_ * 64) + k * 64 + rr],
                       emb[(size_t)seq[(t + 1) * B_ + rr] * H_ + k]);
            }
        }
        gbar(ctr, &target);
        // ---- P2: g1; h1_new = z1*h1_old + (1-z1)*g1 ----
        if (act) {
            float v = phase_gemm<8>(Ax, rhl, Wg1l, red);
            if (tid < 512) {
                int r = tid >> 3, c = tid & 7, n = bl * 8 + c;
                float g = tanhf(v + bg1[l * Hh_ + n]);
                float z = ld_act(&zl[n * 64 + r]);
                float h1o = ld_act(&hP[(size_t)n * 64 + r]);
                st_act(&hC[(size_t)n * 64 + r], z * h1o + (1.f - z) * g);
            }
        }
        gbar(ctr, &target);
        // ---- P3: zr2 = [x, h1_new] @ Wzr2 ----
        if (act) {
            float v = phase_gemm<16>(Ax, hC, Wz2, red);
            int r = tid >> 4, c = tid & 15, n = bl * 16 + c;
            v += bzr2[l * H_ + n];
            float sg = 1.f / (1.f + __expf(-v));
            if (n < Hh_) st_act(&zl[n * 64 + r], sg * MAXF + (1.f - MAXF));
            else st_act(&rhl[(n - Hh_) * 64 + r],
                        sg * ld_act(&hC[(size_t)(n - Hh_) * 64 + r])); // r2*h1n
        }
        gbar(ctr, &target);
        // ---- P4: g2; h2_new = z2*h2_old + (1-z2)*g2 ----
        if (act) {
            float v = phase_gemm<8>(Ax, rhl, Wg2l, red);
            if (tid < 512) {
                int r = tid >> 3, c = tid & 7, n = bl * 8 + c;
                float g = tanhf(v + bg2[l * Hh_ + n]);
                float z = ld_act(&zl[n * 64 + r]);
                float h2o = ld_act(&hP[(size_t)(Hh_ + n) * 64 + r]);
                st_act(&hC[(size_t)(Hh_ + n) * 64 + r], z * h2o + (1.f - z) * g);
            }
        }
        gbar(ctr, &target);
    }
    {   // out[l][r][n] = hT[l][1][n][r]  (final t=255 -> buf 1 for both layers)
        int ll = gtid >> 16, rem = gtid & 65535, r = rem >> 10, n = rem & 1023;
        out[gtid] = ld_act(&hT[(((size_t)ll * 2 + 1) * H_ + n) * 64 + r]);
    }
}

extern "C" void kernel_launch(void* const* d_in, const int* in_sizes, int n_in,
                              void* d_out, int out_size, void* d_ws, size_t ws_size,
                              hipStream_t stream) {
    (void)in_sizes; (void)n_in; (void)out_size; (void)ws_size;
    const int*   seq  = (const int*)  d_in[0];
    const float* h0   = (const float*)d_in[1];
    const float* emb  = (const float*)d_in[2];
    const float* Wzr1 = (const float*)d_in[3];
    const float* bzr1 = (const float*)d_in[4];
    const float* Wg1  = (const float*)d_in[5];
    const float* bg1  = (const float*)d_in[6];
    const float* Wzr2 = (const float*)d_in[7];
    const float* bzr2 = (const float*)d_in[8];
    const float* Wg2  = (const float*)d_in[9];
    const float* bg2  = (const float*)d_in[10];
    float* out = (float*)d_out;
    float* ws  = (float*)d_ws;

    hipMemsetAsync((char*)d_ws + (size_t)OFF_CTR * 4, 0, 64, stream);
    retile_w<<<12288, 256, 0, stream>>>(Wzr1, ws + OFF_WZR1, H_, 16);
    retile_w<<<6144,  256, 0, stream>>>(Wg1,  ws + OFF_WG1,  Hh_, 8);
    retile_w<<<12288, 256, 0, stream>>>(Wzr2, ws + OFF_WZR2, H_, 16);
    retile_w<<<6144,  256, 0, stream>>>(Wg2,  ws + OFF_WG2,  Hh_, 8);

    void* args[] = { &seq, &h0, &emb, &bzr1, &bg1, &bzr2, &bg2, &ws, &out };
    hipLaunchCooperativeKernel((void*)revgru_main, dim3(NBLK), dim3(NT),
                               args, 0, stream);
}